// Round 2
// 400.155 us; speedup vs baseline: 1.0217x; 1.0217x over previous
//
#include <hip/hip_runtime.h>

#define B_SZ   32
#define N_SZ   8192
#define HDIM   256
#define GHID   512
#define K_CL   64
#define M_ROWS (B_SZ * (2 * K_CL + 1))   // 4128
#define M_PAD  4224                      // 132 * 32

typedef short v8s __attribute__((ext_vector_type(8)));
typedef float v4f __attribute__((ext_vector_type(4)));

__device__ __forceinline__ unsigned short f32_to_bf16(float f) {
  unsigned int u = __float_as_uint(f);
  u += 0x7FFFu + ((u >> 16) & 1u);   // RNE
  return (unsigned short)(u >> 16);
}

__device__ __forceinline__ int lower_bound_i(const int* __restrict__ a, int n, int key) {
  int lo = 0, hi = n;
  while (lo < hi) {
    const int mid = (lo + hi) >> 1;
    if (a[mid] < key) lo = mid + 1; else hi = mid;
  }
  return lo;
}

// ---------------------------------------------------------------------------
// Kernel A (fused): blocks [0, 2048): clustered row-sum (b = id>>6, k = id&63).
// Blocks [2048, 2304): bf16-transpose weight prep (hides under the sum's
// HBM-bound tail). One launch instead of two.
// ---------------------------------------------------------------------------
__global__ __launch_bounds__(256) void sum_prep_kernel(
    const float* __restrict__ hs, const int* __restrict__ cs,
    const int* __restrict__ n_ptr, float* __restrict__ Hk,
    const float* __restrict__ W1, const float* __restrict__ W2,
    unsigned short* __restrict__ W1t, unsigned short* __restrict__ W2t) {
  __shared__ float4 red[256];
  __shared__ float tile[32][33];
  const int bid = blockIdx.x;
  const int tid = threadIdx.x;

  if (bid < B_SZ * K_CL) {
    // ---- clustered row sum: one contiguous run of rows per (b, k) ----
    const int b = bid >> 6;
    const int k = bid & 63;
    const int col = (tid & 63) * 4;
    const int rsub = tid >> 6;
    const int n_val = n_ptr[0];

    const int start = lower_bound_i(cs, N_SZ, k);
    int end = lower_bound_i(cs, N_SZ, k + 1);
    if (end > n_val) end = n_val;

    const float* base = hs + (size_t)b * N_SZ * HDIM + col;

    float4 a0 = make_float4(0.f, 0.f, 0.f, 0.f), a1 = a0, a2 = a0, a3 = a0;
    int r = start + rsub;
    for (; r + 12 < end; r += 16) {
      const float4 v0 = *(const float4*)(base + (size_t)(r) * HDIM);
      const float4 v1 = *(const float4*)(base + (size_t)(r + 4) * HDIM);
      const float4 v2 = *(const float4*)(base + (size_t)(r + 8) * HDIM);
      const float4 v3 = *(const float4*)(base + (size_t)(r + 12) * HDIM);
      a0.x += v0.x; a0.y += v0.y; a0.z += v0.z; a0.w += v0.w;
      a1.x += v1.x; a1.y += v1.y; a1.z += v1.z; a1.w += v1.w;
      a2.x += v2.x; a2.y += v2.y; a2.z += v2.z; a2.w += v2.w;
      a3.x += v3.x; a3.y += v3.y; a3.z += v3.z; a3.w += v3.w;
    }
    for (; r < end; r += 4) {
      const float4 v = *(const float4*)(base + (size_t)r * HDIM);
      a0.x += v.x; a0.y += v.y; a0.z += v.z; a0.w += v.w;
    }
    float4 acc;
    acc.x = (a0.x + a1.x) + (a2.x + a3.x);
    acc.y = (a0.y + a1.y) + (a2.y + a3.y);
    acc.z = (a0.z + a1.z) + (a2.z + a3.z);
    acc.w = (a0.w + a1.w) + (a2.w + a3.w);

    red[tid] = acc;
    __syncthreads();
    if (tid < 64) {
      const float4 p0 = red[tid], p1 = red[tid + 64], p2 = red[tid + 128], p3 = red[tid + 192];
      float4 o;
      o.x = (p0.x + p1.x) + (p2.x + p3.x);
      o.y = (p0.y + p1.y) + (p2.y + p3.y);
      o.z = (p0.z + p1.z) + (p2.z + p3.z);
      o.w = (p0.w + p1.w) + (p2.w + p3.w);
      *(float4*)(Hk + ((size_t)b * K_CL + k) * HDIM + tid * 4) = o;
    }
  } else {
    // ---- weight prep: W1t[512][256], W2t[256][512] (bf16, transposed) ----
    const int idx = bid - B_SZ * K_CL;
    if (idx < 128) {
      const int tr = idx >> 4, tc = idx & 15;
      const int r0 = tid >> 5, c = tid & 31;
#pragma unroll
      for (int p = 0; p < 4; ++p) {
        const int r = p * 8 + r0;
        tile[r][c] = W1[(size_t)(tr * 32 + r) * GHID + tc * 32 + c];
      }
      __syncthreads();
#pragma unroll
      for (int p = 0; p < 4; ++p) {
        const int r = p * 8 + r0;
        W1t[(size_t)(tc * 32 + r) * HDIM + tr * 32 + c] = f32_to_bf16(tile[c][r]);
      }
    } else {
      const int t = idx - 128;
      const int tr = t >> 3, tc = t & 7;
      const int r0 = tid >> 5, c = tid & 31;
#pragma unroll
      for (int p = 0; p < 4; ++p) {
        const int r = p * 8 + r0;
        tile[r][c] = W2[(size_t)(tr * 32 + r) * HDIM + tc * 32 + c];
      }
      __syncthreads();
#pragma unroll
      for (int p = 0; p < 4; ++p) {
        const int r = p * 8 + r0;
        W2t[(size_t)(tc * 32 + r) * GHID + tr * 32 + c] = f32_to_bf16(tile[c][r]);
      }
    }
  }
}

// ---------------------------------------------------------------------------
// Fused MLP: per block of BM=32 rows, compute
//   act = relu(H @ W1 + b1)  (H built on the fly from Hk/hs)  -> LDS (bf16)
//   gs  = act @ W2 + b2                                       -> global (fp32)
// Eliminates the act global round-trip and one kernel launch.
// 4 waves; phase 1: wave w owns hidden cols [w*128, w*128+128) (acc1[2][8]);
// phase 2: wave w owns out cols [w*64, w*64+64) (acc2[2][4]).
// Fragment layouts per m89/m91: A[m=lane&15][k=quad*8+j], B[k][n=lane&15],
// C/D col=lane&15, row=quad*4+reg.
// ---------------------------------------------------------------------------
__global__ __launch_bounds__(256) void mlp_kernel(
    const float* __restrict__ hs, const float* __restrict__ Hk,
    const unsigned short* __restrict__ W1t, const float* __restrict__ b1,
    const unsigned short* __restrict__ W2t, const float* __restrict__ b2,
    const int* __restrict__ n_ptr, float* __restrict__ gs) {
  constexpr int LDT = 40;    // phase-1 staging row pitch (bf16 elems)
  constexpr int LDT2 = 72;   // phase-2 W2t staging pitch
  constexpr int LDA = 520;   // act LDS pitch
  __shared__ unsigned short As[32 * LDT];    //  2.5 KB
  __shared__ unsigned short Bs[512 * LDT];   // 40.0 KB (reused in phase 2: 256*72 <= 512*40)
  __shared__ unsigned short Act[32 * LDA];   // 33.3 KB

  const int tid = threadIdx.x;
  const int wave = tid >> 6, lane = tid & 63;
  const int quad = lane >> 4, lr = lane & 15;
  const int row0 = blockIdx.x * 32;
  const int n_val = n_ptr[0];

  // A staging role: row ar = tid>>3 (0..31), k-offset ak = (tid&7)*4
  const int ar = tid >> 3;
  const int ak = (tid & 7) * 4;
  const int grow = row0 + ar;
  const int b = grow / 129;
  const int j = grow - b * 129;
  const bool valid = (grow < M_ROWS);
  const bool add_hn = valid && (j >= K_CL);
  const bool use_hk = valid && (j < 2 * K_CL);
  const int jj = (j < K_CL) ? j : (j - K_CL);
  const float* hk_row = Hk + ((size_t)b * K_CL + jj) * HDIM + ak;
  const float* hn_row = hs + ((size_t)b * N_SZ + n_val) * HDIM + ak;

  // ---------------- phase 1: act = relu(H @ W1 + b1) ----------------
  v4f acc1[2][8];
#pragma unroll
  for (int rt = 0; rt < 2; ++rt)
#pragma unroll
    for (int cf = 0; cf < 8; ++cf) acc1[rt][cf] = (v4f){0.f, 0.f, 0.f, 0.f};

  const int brr = tid >> 2;        // 0..63
  const int bkk = (tid & 3) * 8;   // 0/8/16/24

  for (int k0 = 0; k0 < HDIM; k0 += 32) {
    // A stage: build 4 H values, convert to bf16
    float4 f = make_float4(0.f, 0.f, 0.f, 0.f);
    if (use_hk) f = *(const float4*)(hk_row + k0);
    if (add_hn) {
      const float4 h = *(const float4*)(hn_row + k0);
      f.x += h.x; f.y += h.y; f.z += h.z; f.w += h.w;
    }
    unsigned short u[4];
    u[0] = f32_to_bf16(f.x); u[1] = f32_to_bf16(f.y);
    u[2] = f32_to_bf16(f.z); u[3] = f32_to_bf16(f.w);
    *(uint2*)(As + ar * LDT + ak) = *(const uint2*)u;
    // B stage: all 512 hidden rows x 32 k
#pragma unroll
    for (int p = 0; p < 8; ++p) {
      *(uint4*)(Bs + (p * 64 + brr) * LDT + bkk) =
          *(const uint4*)(W1t + (size_t)(p * 64 + brr) * HDIM + k0 + bkk);
    }
    __syncthreads();

#pragma unroll
    for (int rt = 0; rt < 2; ++rt) {
      const v8s a = *(const v8s*)(As + (rt * 16 + lr) * LDT + quad * 8);
#pragma unroll
      for (int cf = 0; cf < 8; ++cf) {
        const v8s bf = *(const v8s*)(Bs + (wave * 128 + cf * 16 + lr) * LDT + quad * 8);
        acc1[rt][cf] = __builtin_amdgcn_mfma_f32_16x16x32_bf16(a, bf, acc1[rt][cf], 0, 0, 0);
      }
    }
    __syncthreads();
  }

  // relu + bias -> bf16 act in LDS
#pragma unroll
  for (int rt = 0; rt < 2; ++rt) {
#pragma unroll
    for (int cf = 0; cf < 8; ++cf) {
      const int col = wave * 128 + cf * 16 + lr;
      const float bv = b1[col];
#pragma unroll
      for (int i = 0; i < 4; ++i) {
        const int row = rt * 16 + quad * 4 + i;
        Act[row * LDA + col] = f32_to_bf16(fmaxf(acc1[rt][cf][i] + bv, 0.f));
      }
    }
  }
  __syncthreads();

  // ---------------- phase 2: gs = act @ W2 + b2 ----------------
  v4f acc2[2][4];
#pragma unroll
  for (int rt = 0; rt < 2; ++rt)
#pragma unroll
    for (int cf = 0; cf < 4; ++cf) acc2[rt][cf] = (v4f){0.f, 0.f, 0.f, 0.f};

  const int br2 = tid >> 3;        // 0..31
  const int bk2 = (tid & 7) * 8;   // 0..56

  for (int k0 = 0; k0 < GHID; k0 += 64) {
    // stage W2t rows 0..255 x 64 k
#pragma unroll
    for (int p = 0; p < 8; ++p) {
      *(uint4*)(Bs + (p * 32 + br2) * LDT2 + bk2) =
          *(const uint4*)(W2t + (size_t)(p * 32 + br2) * GHID + k0 + bk2);
    }
    __syncthreads();

#pragma unroll
    for (int kk = 0; kk < 64; kk += 32) {
#pragma unroll
      for (int rt = 0; rt < 2; ++rt) {
        const v8s a = *(const v8s*)(Act + (rt * 16 + lr) * LDA + k0 + kk + quad * 8);
#pragma unroll
        for (int cf = 0; cf < 4; ++cf) {
          const v8s bf = *(const v8s*)(Bs + (wave * 64 + cf * 16 + lr) * LDT2 + kk + quad * 8);
          acc2[rt][cf] = __builtin_amdgcn_mfma_f32_16x16x32_bf16(a, bf, acc2[rt][cf], 0, 0, 0);
        }
      }
    }
    __syncthreads();
  }

#pragma unroll
  for (int rt = 0; rt < 2; ++rt) {
#pragma unroll
    for (int cf = 0; cf < 4; ++cf) {
      const int col = wave * 64 + cf * 16 + lr;
      const float bv = b2[col];
#pragma unroll
      for (int i = 0; i < 4; ++i) {
        const int row = row0 + rt * 16 + quad * 4 + i;
        gs[(size_t)row * HDIM + col] = acc2[rt][cf][i] + bv;
      }
    }
  }
}

// ---------------------------------------------------------------------------
// Combine: S = sum_{k<64} gs[b,k,:]; G[b,k] = S - gs[b,k] + gs[b,64+k];
// G[b,64] = S + gs[b,128]. Grid (B,4) x 64 thr.
// ---------------------------------------------------------------------------
__global__ __launch_bounds__(64) void combine_kernel(
    const float* __restrict__ gs, float* __restrict__ G, float* __restrict__ mask) {
  const int b = blockIdx.x;
  const int h = blockIdx.y * 64 + threadIdx.x;
  const float* g = gs + (size_t)b * (2 * K_CL + 1) * HDIM + h;
  float S = 0.f;
#pragma unroll 8
  for (int k = 0; k < K_CL; ++k) S += g[k * HDIM];
#pragma unroll 4
  for (int k = 0; k < K_CL; ++k) {
    G[((size_t)b * (K_CL + 1) + k) * HDIM + h] = S - g[k * HDIM] + g[(K_CL + k) * HDIM];
  }
  G[((size_t)b * (K_CL + 1) + K_CL) * HDIM + h] = S + g[2 * K_CL * HDIM];
  const int mi = blockIdx.y * 64 + threadIdx.x;
  if (mi < K_CL + 1) mask[b * (K_CL + 1) + mi] = 1.0f;
}

extern "C" void kernel_launch(void* const* d_in, const int* in_sizes, int n_in,
                              void* d_out, int out_size, void* d_ws, size_t ws_size,
                              hipStream_t stream) {
  const float* hs = (const float*)d_in[0];
  const int* cs = (const int*)d_in[1];     // row 0 (all rows identical)
  const float* W1 = (const float*)d_in[2];
  const float* b1 = (const float*)d_in[3];
  const float* W2 = (const float*)d_in[4];
  const float* b2 = (const float*)d_in[5];
  const int* n_ptr = (const int*)d_in[6];

  float* G = (float*)d_out;                          // 32*65*256
  float* mask = G + (size_t)B_SZ * (K_CL + 1) * HDIM;

  // ws layout
  char* w = (char*)d_ws;
  float* Hk = (float*)w;                     w += (size_t)B_SZ * K_CL * HDIM * 4;  // 2 MiB
  unsigned short* W1t = (unsigned short*)w;  w += (size_t)GHID * HDIM * 2;         // 256 KiB
  unsigned short* W2t = (unsigned short*)w;  w += (size_t)HDIM * GHID * 2;         // 256 KiB
  float* gs = (float*)w;                                                           // 4.3 MiB

  sum_prep_kernel<<<B_SZ * K_CL + 256, 256, 0, stream>>>(
      hs, cs, n_ptr, Hk, W1, W2, W1t, W2t);
  mlp_kernel<<<M_PAD / 32, 256, 0, stream>>>(hs, Hk, W1t, b1, W2t, b2, n_ptr, gs);
  combine_kernel<<<dim3(B_SZ, HDIM / 64), 64, 0, stream>>>(gs, G, mask);
}

// Round 3
// 376.007 us; speedup vs baseline: 1.0873x; 1.0642x over previous
//
#include <hip/hip_runtime.h>

#define B_SZ   32
#define N_SZ   8192
#define HDIM   256
#define GHID   512
#define K_CL   64
#define M_ROWS (B_SZ * (2 * K_CL + 1))   // 4128 = 258 * 16

typedef short v8s __attribute__((ext_vector_type(8)));
typedef float v4f __attribute__((ext_vector_type(4)));

__device__ __forceinline__ unsigned short f32_to_bf16(float f) {
  unsigned int u = __float_as_uint(f);
  u += 0x7FFFu + ((u >> 16) & 1u);   // RNE
  return (unsigned short)(u >> 16);
}

__device__ __forceinline__ int lower_bound_i(const int* __restrict__ a, int n, int key) {
  int lo = 0, hi = n;
  while (lo < hi) {
    const int mid = (lo + hi) >> 1;
    if (a[mid] < key) lo = mid + 1; else hi = mid;
  }
  return lo;
}

// ---------------------------------------------------------------------------
// Kernel A (fused): blocks [0, 2048): clustered row-sum (b = id>>6, k = id&63),
// nontemporal float4 streaming of hs (read-once, keep out of L2).
// Blocks [2048, 2304): bf16-transpose weight prep (hides under the sum tail).
// ---------------------------------------------------------------------------
__global__ __launch_bounds__(256) void sum_prep_kernel(
    const float* __restrict__ hs, const int* __restrict__ cs,
    const int* __restrict__ n_ptr, float* __restrict__ Hk,
    const float* __restrict__ W1, const float* __restrict__ W2,
    unsigned short* __restrict__ W1t, unsigned short* __restrict__ W2t) {
  __shared__ v4f red[256];
  __shared__ float tile[32][33];
  const int bid = blockIdx.x;
  const int tid = threadIdx.x;

  if (bid < B_SZ * K_CL) {
    // ---- clustered row sum: one contiguous run of rows per (b, k) ----
    const int b = bid >> 6;
    const int k = bid & 63;
    const int col = (tid & 63) * 4;
    const int rsub = tid >> 6;
    const int n_val = n_ptr[0];

    const int start = lower_bound_i(cs, N_SZ, k);
    int end = lower_bound_i(cs, N_SZ, k + 1);
    if (end > n_val) end = n_val;

    const float* base = hs + (size_t)b * N_SZ * HDIM + col;

    v4f a0 = (v4f){0.f, 0.f, 0.f, 0.f}, a1 = a0, a2 = a0, a3 = a0;
    int r = start + rsub;
    for (; r + 12 < end; r += 16) {
      const v4f v0 = __builtin_nontemporal_load((const v4f*)(base + (size_t)(r) * HDIM));
      const v4f v1 = __builtin_nontemporal_load((const v4f*)(base + (size_t)(r + 4) * HDIM));
      const v4f v2 = __builtin_nontemporal_load((const v4f*)(base + (size_t)(r + 8) * HDIM));
      const v4f v3 = __builtin_nontemporal_load((const v4f*)(base + (size_t)(r + 12) * HDIM));
      a0 += v0; a1 += v1; a2 += v2; a3 += v3;
    }
    for (; r < end; r += 4) {
      const v4f v = __builtin_nontemporal_load((const v4f*)(base + (size_t)r * HDIM));
      a0 += v;
    }
    const v4f acc = (a0 + a1) + (a2 + a3);

    red[tid] = acc;
    __syncthreads();
    if (tid < 64) {
      const v4f o = (red[tid] + red[tid + 64]) + (red[tid + 128] + red[tid + 192]);
      *(v4f*)(Hk + ((size_t)b * K_CL + k) * HDIM + tid * 4) = o;
    }
  } else {
    // ---- weight prep: W1t[512][256], W2t[256][512] (bf16, transposed) ----
    const int idx = bid - B_SZ * K_CL;
    if (idx < 128) {
      const int tr = idx >> 4, tc = idx & 15;
      const int r0 = tid >> 5, c = tid & 31;
#pragma unroll
      for (int p = 0; p < 4; ++p) {
        const int r = p * 8 + r0;
        tile[r][c] = W1[(size_t)(tr * 32 + r) * GHID + tc * 32 + c];
      }
      __syncthreads();
#pragma unroll
      for (int p = 0; p < 4; ++p) {
        const int r = p * 8 + r0;
        W1t[(size_t)(tc * 32 + r) * HDIM + tr * 32 + c] = f32_to_bf16(tile[c][r]);
      }
    } else {
      const int t = idx - 128;
      const int tr = t >> 3, tc = t & 7;
      const int r0 = tid >> 5, c = tid & 31;
#pragma unroll
      for (int p = 0; p < 4; ++p) {
        const int r = p * 8 + r0;
        tile[r][c] = W2[(size_t)(tr * 32 + r) * HDIM + tc * 32 + c];
      }
      __syncthreads();
#pragma unroll
      for (int p = 0; p < 4; ++p) {
        const int r = p * 8 + r0;
        W2t[(size_t)(tc * 32 + r) * GHID + tr * 32 + c] = f32_to_bf16(tile[c][r]);
      }
    }
  }
}

// ---------------------------------------------------------------------------
// Fused MLP, BM=16: per block of 16 H-rows,
//   act = relu(H @ W1 + b1)  (H built on the fly from Hk/hs)  -> LDS (bf16)
//   gs  = act @ W2 + b2                                       -> global (fp32)
// 4128 rows = 258 blocks exactly (no padding). LDS 57.5 KB -> 2 blocks/CU,
// full 256-CU coverage (vs 132 blocks @ 76 KB before). Per-block MFMA work
// halves; weight staging per block constant (L2-resident, under ceiling).
// Phase 1: wave w owns hidden cols [w*128, w*128+128) (acc1[8]);
// Phase 2: wave w owns out cols [w*64, w*64+64) (acc2[4]).
// Fragment layouts per m89/m91: A[m=lane&15][k=quad*8+j], B[k][n=lane&15],
// C/D col=lane&15, row=quad*4+reg.
// ---------------------------------------------------------------------------
__global__ __launch_bounds__(256) void mlp_kernel(
    const float* __restrict__ hs, const float* __restrict__ Hk,
    const unsigned short* __restrict__ W1t, const float* __restrict__ b1,
    const unsigned short* __restrict__ W2t, const float* __restrict__ b2,
    const int* __restrict__ n_ptr, float* __restrict__ gs) {
  constexpr int BM = 16;
  constexpr int LDT = 40;    // phase-1 staging row pitch (bf16 elems)
  constexpr int LDT2 = 72;   // phase-2 W2t staging pitch
  constexpr int LDA = 520;   // act LDS pitch
  __shared__ unsigned short As[BM * LDT];    //  1.25 KB
  __shared__ unsigned short Bs[512 * LDT];   // 40.0 KB (reused phase 2: 256*72 <= 512*40)
  __shared__ unsigned short Act[BM * LDA];   // 16.25 KB

  const int tid = threadIdx.x;
  const int wave = tid >> 6, lane = tid & 63;
  const int quad = lane >> 4, lr = lane & 15;
  const int row0 = blockIdx.x * BM;
  const int n_val = n_ptr[0];

  // A staging role (threads 0..127): row ar = tid>>3, k-offset ak = (tid&7)*4
  const bool astage = tid < 128;
  const int ar = tid >> 3;          // 0..15 for staging threads
  const int ak = (tid & 7) * 4;
  const int grow = row0 + (astage ? ar : 0);
  const int b = grow / 129;
  const int j = grow - b * 129;
  const bool add_hn = astage && (j >= K_CL);
  const bool use_hk = astage && (j < 2 * K_CL);
  const int jj = (j < K_CL) ? j : (j - K_CL);
  const float* hk_row = Hk + ((size_t)b * K_CL + jj) * HDIM + ak;
  const float* hn_row = hs + ((size_t)b * N_SZ + n_val) * HDIM + ak;

  // ---------------- phase 1: act = relu(H @ W1 + b1) ----------------
  v4f acc1[8];
#pragma unroll
  for (int cf = 0; cf < 8; ++cf) acc1[cf] = (v4f){0.f, 0.f, 0.f, 0.f};

  const int brr = tid >> 2;        // 0..63
  const int bkk = (tid & 3) * 8;   // 0/8/16/24

  for (int k0 = 0; k0 < HDIM; k0 += 32) {
    // A stage: build 4 H values, convert to bf16
    if (astage) {
      float4 f = make_float4(0.f, 0.f, 0.f, 0.f);
      if (use_hk) f = *(const float4*)(hk_row + k0);
      if (add_hn) {
        const float4 h = *(const float4*)(hn_row + k0);
        f.x += h.x; f.y += h.y; f.z += h.z; f.w += h.w;
      }
      unsigned short u[4];
      u[0] = f32_to_bf16(f.x); u[1] = f32_to_bf16(f.y);
      u[2] = f32_to_bf16(f.z); u[3] = f32_to_bf16(f.w);
      *(uint2*)(As + ar * LDT + ak) = *(const uint2*)u;
    }
    // B stage: all 512 hidden rows x 32 k
#pragma unroll
    for (int p = 0; p < 8; ++p) {
      *(uint4*)(Bs + (p * 64 + brr) * LDT + bkk) =
          *(const uint4*)(W1t + (size_t)(p * 64 + brr) * HDIM + k0 + bkk);
    }
    __syncthreads();

    const v8s a = *(const v8s*)(As + lr * LDT + quad * 8);
#pragma unroll
    for (int cf = 0; cf < 8; ++cf) {
      const v8s bf = *(const v8s*)(Bs + (wave * 128 + cf * 16 + lr) * LDT + quad * 8);
      acc1[cf] = __builtin_amdgcn_mfma_f32_16x16x32_bf16(a, bf, acc1[cf], 0, 0, 0);
    }
    __syncthreads();
  }

  // relu + bias -> bf16 act in LDS
#pragma unroll
  for (int cf = 0; cf < 8; ++cf) {
    const int col = wave * 128 + cf * 16 + lr;
    const float bv = b1[col];
#pragma unroll
    for (int i = 0; i < 4; ++i) {
      const int row = quad * 4 + i;
      Act[row * LDA + col] = f32_to_bf16(fmaxf(acc1[cf][i] + bv, 0.f));
    }
  }
  __syncthreads();

  // ---------------- phase 2: gs = act @ W2 + b2 ----------------
  v4f acc2[4];
#pragma unroll
  for (int cf = 0; cf < 4; ++cf) acc2[cf] = (v4f){0.f, 0.f, 0.f, 0.f};

  const int br2 = tid >> 3;        // 0..31
  const int bk2 = (tid & 7) * 8;   // 0..56

  for (int k0 = 0; k0 < GHID; k0 += 64) {
    // stage W2t rows 0..255 x 64 k
#pragma unroll
    for (int p = 0; p < 8; ++p) {
      *(uint4*)(Bs + (p * 32 + br2) * LDT2 + bk2) =
          *(const uint4*)(W2t + (size_t)(p * 32 + br2) * GHID + k0 + bk2);
    }
    __syncthreads();

#pragma unroll
    for (int kk = 0; kk < 64; kk += 32) {
      const v8s a = *(const v8s*)(Act + lr * LDA + k0 + kk + quad * 8);
#pragma unroll
      for (int cf = 0; cf < 4; ++cf) {
        const v8s bf = *(const v8s*)(Bs + (wave * 64 + cf * 16 + lr) * LDT2 + kk + quad * 8);
        acc2[cf] = __builtin_amdgcn_mfma_f32_16x16x32_bf16(a, bf, acc2[cf], 0, 0, 0);
      }
    }
    __syncthreads();
  }

#pragma unroll
  for (int cf = 0; cf < 4; ++cf) {
    const int col = wave * 64 + cf * 16 + lr;
    const float bv = b2[col];
#pragma unroll
    for (int i = 0; i < 4; ++i) {
      const int row = row0 + quad * 4 + i;
      gs[(size_t)row * HDIM + col] = acc2[cf][i] + bv;
    }
  }
}

// ---------------------------------------------------------------------------
// Combine: S = sum_{k<64} gs[b,k,:]; G[b,k] = S - gs[b,k] + gs[b,64+k];
// G[b,64] = S + gs[b,128]. Grid (B,4) x 64 thr.
// ---------------------------------------------------------------------------
__global__ __launch_bounds__(64) void combine_kernel(
    const float* __restrict__ gs, float* __restrict__ G, float* __restrict__ mask) {
  const int b = blockIdx.x;
  const int h = blockIdx.y * 64 + threadIdx.x;
  const float* g = gs + (size_t)b * (2 * K_CL + 1) * HDIM + h;
  float S = 0.f;
#pragma unroll 8
  for (int k = 0; k < K_CL; ++k) S += g[k * HDIM];
#pragma unroll 4
  for (int k = 0; k < K_CL; ++k) {
    G[((size_t)b * (K_CL + 1) + k) * HDIM + h] = S - g[k * HDIM] + g[(K_CL + k) * HDIM];
  }
  G[((size_t)b * (K_CL + 1) + K_CL) * HDIM + h] = S + g[2 * K_CL * HDIM];
  const int mi = blockIdx.y * 64 + threadIdx.x;
  if (mi < K_CL + 1) mask[b * (K_CL + 1) + mi] = 1.0f;
}

extern "C" void kernel_launch(void* const* d_in, const int* in_sizes, int n_in,
                              void* d_out, int out_size, void* d_ws, size_t ws_size,
                              hipStream_t stream) {
  const float* hs = (const float*)d_in[0];
  const int* cs = (const int*)d_in[1];     // row 0 (all rows identical)
  const float* W1 = (const float*)d_in[2];
  const float* b1 = (const float*)d_in[3];
  const float* W2 = (const float*)d_in[4];
  const float* b2 = (const float*)d_in[5];
  const int* n_ptr = (const int*)d_in[6];

  float* G = (float*)d_out;                          // 32*65*256
  float* mask = G + (size_t)B_SZ * (K_CL + 1) * HDIM;

  // ws layout
  char* w = (char*)d_ws;
  float* Hk = (float*)w;                     w += (size_t)B_SZ * K_CL * HDIM * 4;  // 2 MiB
  unsigned short* W1t = (unsigned short*)w;  w += (size_t)GHID * HDIM * 2;         // 256 KiB
  unsigned short* W2t = (unsigned short*)w;  w += (size_t)HDIM * GHID * 2;         // 256 KiB
  float* gs = (float*)w;                                                           // 4.2 MiB

  sum_prep_kernel<<<B_SZ * K_CL + 256, 256, 0, stream>>>(
      hs, cs, n_ptr, Hk, W1, W2, W1t, W2t);
  mlp_kernel<<<M_ROWS / 16, 256, 0, stream>>>(hs, Hk, W1t, b1, W2t, b2, n_ptr, gs);
  combine_kernel<<<dim3(B_SZ, HDIM / 64), 64, 0, stream>>>(gs, G, mask);
}